// Round 1
// baseline (831.956 us; speedup 1.0000x reference)
//
#include <hip/hip_runtime.h>

#define N_NODES 100000
#define N_EDGES 1600000
#define HID 128
#define IN_DIM 5
#define SCAN_ELEMS 1024
#define SCAN_NBLK ((N_NODES + SCAN_ELEMS - 1) / SCAN_ELEMS)  // 98

// ---------------- CSR build ----------------

__global__ void k_degree(const int* __restrict__ ei, int* __restrict__ deg) {
    int e = blockIdx.x * blockDim.x + threadIdx.x;
    if (e < N_EDGES) atomicAdd(&deg[ei[N_EDGES + e]], 1);
}

__global__ void k_dinv(const int* __restrict__ deg, float* __restrict__ dinv) {
    int i = blockIdx.x * blockDim.x + threadIdx.x;
    if (i < N_NODES) dinv[i] = rsqrtf((float)(deg[i] + 1));  // +1 self-loop
}

__global__ void k_scan_bsum(const int* __restrict__ deg, int* __restrict__ bsum) {
    __shared__ int sm[256];
    int t = threadIdx.x, b = blockIdx.x;
    int base = b * SCAN_ELEMS + t * 4;
    int s = 0;
    if (base + 3 < N_NODES) {
        int4 v = *(const int4*)(deg + base);
        s = v.x + v.y + v.z + v.w;
    } else {
        for (int j = 0; j < 4; ++j) if (base + j < N_NODES) s += deg[base + j];
    }
    sm[t] = s; __syncthreads();
    for (int off = 128; off > 0; off >>= 1) {
        if (t < off) sm[t] += sm[t + off];
        __syncthreads();
    }
    if (t == 0) bsum[b] = sm[0];
}

__global__ void k_scan_tops(const int* __restrict__ bsum, int* __restrict__ bofs,
                            int* __restrict__ row_ptr) {
    __shared__ int sm[128];
    int t = threadIdx.x;
    int v = (t < SCAN_NBLK) ? bsum[t] : 0;
    sm[t] = v; __syncthreads();
    for (int off = 1; off < 128; off <<= 1) {
        int add = (t >= off) ? sm[t - off] : 0;
        __syncthreads();
        sm[t] += add;
        __syncthreads();
    }
    if (t < SCAN_NBLK) bofs[t] = sm[t] - v;  // exclusive
    if (t == 0) row_ptr[N_NODES] = N_EDGES;
}

__global__ void k_scan_final(const int* __restrict__ deg, const int* __restrict__ bofs,
                             int* __restrict__ row_ptr, int* __restrict__ cursor) {
    __shared__ int sm[256];
    int t = threadIdx.x, b = blockIdx.x;
    int base = b * SCAN_ELEMS + t * 4;
    int e0 = 0, e1 = 0, e2 = 0, e3 = 0;
    if (base + 3 < N_NODES) {
        int4 v = *(const int4*)(deg + base);
        e0 = v.x; e1 = v.y; e2 = v.z; e3 = v.w;
    } else {
        if (base     < N_NODES) e0 = deg[base];
        if (base + 1 < N_NODES) e1 = deg[base + 1];
        if (base + 2 < N_NODES) e2 = deg[base + 2];
        if (base + 3 < N_NODES) e3 = deg[base + 3];
    }
    int tot = e0 + e1 + e2 + e3;
    sm[t] = tot; __syncthreads();
    for (int off = 1; off < 256; off <<= 1) {
        int add = (t >= off) ? sm[t - off] : 0;
        __syncthreads();
        sm[t] += add;
        __syncthreads();
    }
    int p0 = sm[t] - tot + bofs[b];
    int p1 = p0 + e0, p2 = p1 + e1, p3 = p2 + e2;
    if (base + 3 < N_NODES) {
        *(int4*)(row_ptr + base) = make_int4(p0, p1, p2, p3);
        *(int4*)(cursor + base)  = make_int4(p0, p1, p2, p3);
    } else {
        if (base     < N_NODES) { row_ptr[base]     = p0; cursor[base]     = p0; }
        if (base + 1 < N_NODES) { row_ptr[base + 1] = p1; cursor[base + 1] = p1; }
        if (base + 2 < N_NODES) { row_ptr[base + 2] = p2; cursor[base + 2] = p2; }
        if (base + 3 < N_NODES) { row_ptr[base + 3] = p3; cursor[base + 3] = p3; }
    }
}

__global__ void k_fill(const int* __restrict__ ei, int* __restrict__ cursor,
                       int* __restrict__ col) {
    int e = blockIdx.x * blockDim.x + threadIdx.x;
    if (e < N_EDGES) {
        int s = ei[e], d = ei[N_EDGES + e];
        int pos = atomicAdd(&cursor[d], 1);
        col[pos] = s;
    }
}

// ---------------- layer 1 matmul (K=5): g = dinv * (x @ W1) ----------------

__global__ void k_mm1(const float* __restrict__ x, const float* __restrict__ W1,
                      const float* __restrict__ dinv, float* __restrict__ g) {
    __shared__ float Wl[IN_DIM * HID];
    int t = threadIdx.x;
    for (int j = t; j < IN_DIM * HID; j += 256) Wl[j] = W1[j];
    __syncthreads();
    int row = blockIdx.x * 2 + (t >> 7);
    int cc  = t & 127;
    if (row >= N_NODES) return;
    float acc = 0.f;
    #pragma unroll
    for (int k = 0; k < IN_DIM; ++k)
        acc += x[row * IN_DIM + k] * Wl[k * HID + cc];
    g[(size_t)row * HID + cc] = dinv[row] * acc;
}

// ---------------- hidden matmul (128x128): G = dinv * (X @ W) ----------------
// 32 rows/block, W staged in two 32KB LDS halves, 4x4 register blocking/thread.

__global__ __launch_bounds__(256) void k_mm_hid(const float* __restrict__ X,
                                                const float* __restrict__ W,
                                                const float* __restrict__ dinv,
                                                float* __restrict__ G) {
    __shared__ float Wl[64 * HID];   // 32KB (half of W)
    __shared__ float xt[32 * HID];   // 16KB
    int t = threadIdx.x;
    int row0 = blockIdx.x * 32;
    const float4* X4 = (const float4*)(X + (size_t)row0 * HID);
    float4* xt4 = (float4*)xt;
    #pragma unroll
    for (int i = 0; i < 4; ++i) xt4[i * 256 + t] = X4[i * 256 + t];
    const float4* Wg4 = (const float4*)W;
    float4* Wl4 = (float4*)Wl;
    int cg = t & 31, rg = t >> 5;
    float4 a0 = {0,0,0,0}, a1 = {0,0,0,0}, a2 = {0,0,0,0}, a3 = {0,0,0,0};
    for (int h = 0; h < 2; ++h) {
        __syncthreads();  // xt ready (h=0) / prev-half compute done (h=1)
        #pragma unroll
        for (int i = 0; i < 8; ++i) Wl4[i * 256 + t] = Wg4[h * 2048 + i * 256 + t];
        __syncthreads();
        #pragma unroll 8
        for (int kk = 0; kk < 64; ++kk) {
            float4 w = Wl4[kk * 32 + cg];
            int k = h * 64 + kk;
            float x0 = xt[(rg * 4 + 0) * HID + k];
            float x1 = xt[(rg * 4 + 1) * HID + k];
            float x2 = xt[(rg * 4 + 2) * HID + k];
            float x3 = xt[(rg * 4 + 3) * HID + k];
            a0.x += x0 * w.x; a0.y += x0 * w.y; a0.z += x0 * w.z; a0.w += x0 * w.w;
            a1.x += x1 * w.x; a1.y += x1 * w.y; a1.z += x1 * w.z; a1.w += x1 * w.w;
            a2.x += x2 * w.x; a2.y += x2 * w.y; a2.z += x2 * w.z; a2.w += x2 * w.w;
            a3.x += x3 * w.x; a3.y += x3 * w.y; a3.z += x3 * w.z; a3.w += x3 * w.w;
        }
    }
    float4 acc[4] = {a0, a1, a2, a3};
    #pragma unroll
    for (int r = 0; r < 4; ++r) {
        int row = row0 + rg * 4 + r;
        float s = dinv[row];
        float4 a = acc[r];
        a.x *= s; a.y *= s; a.z *= s; a.w *= s;
        *(float4*)(G + (size_t)row * HID + cg * 4) = a;
    }
}

// ---------------- aggregation: out = relu(dinv*(g[i] + sum g[src]) + b) ------
// one wave per node; FINAL=1 fuses the 128->1 FC + bias.

template <int FINAL>
__global__ void k_agg(const float* __restrict__ g, const int* __restrict__ row_ptr,
                      const int* __restrict__ col, const float* __restrict__ dinv,
                      const float* __restrict__ bias, const float* __restrict__ Wfc,
                      const float* __restrict__ bfc, float* __restrict__ out) {
    int wid  = (int)((blockIdx.x * blockDim.x + threadIdx.x) >> 6);
    int lane = threadIdx.x & 63;
    if (wid >= N_NODES) return;
    const size_t base = (size_t)wid * HID + lane * 2;
    float2 acc = *(const float2*)(g + base);  // self-loop term
    int start = row_ptr[wid], end = row_ptr[wid + 1];
    for (int j = start; j < end; ++j) {
        int s = col[j];
        float2 v = *(const float2*)(g + (size_t)s * HID + lane * 2);
        acc.x += v.x; acc.y += v.y;
    }
    float sc = dinv[wid];
    float2 bb = *(const float2*)(bias + lane * 2);
    float o0 = fmaxf(fmaf(sc, acc.x, bb.x), 0.f);
    float o1 = fmaxf(fmaf(sc, acc.y, bb.y), 0.f);
    if (FINAL == 0) {
        *(float2*)(out + base) = make_float2(o0, o1);
    } else {
        float2 wv = *(const float2*)(Wfc + lane * 2);
        float d = o0 * wv.x + o1 * wv.y;
        #pragma unroll
        for (int off = 32; off > 0; off >>= 1) d += __shfl_down(d, off, 64);
        if (lane == 0) out[wid] = d + bfc[0];
    }
}

// ---------------- launcher ----------------

extern "C" void kernel_launch(void* const* d_in, const int* in_sizes, int n_in,
                              void* d_out, int out_size, void* d_ws, size_t ws_size,
                              hipStream_t stream) {
    (void)in_sizes; (void)n_in; (void)out_size; (void)ws_size;
    const float* x   = (const float*)d_in[0];
    const int*   ei  = (const int*)d_in[1];
    const float* W1  = (const float*)d_in[2];
    const float* b1  = (const float*)d_in[3];
    const float* W2  = (const float*)d_in[4];
    const float* b2  = (const float*)d_in[5];
    const float* W3  = (const float*)d_in[6];
    const float* b3  = (const float*)d_in[7];
    const float* Wfc = (const float*)d_in[8];
    const float* bfc = (const float*)d_in[9];
    float* out = (float*)d_out;

    char* p = (char*)d_ws;
    auto alloc = [&](size_t bytes) -> void* {
        void* r = (void*)p;
        p += (bytes + 511) & ~(size_t)511;
        return r;
    };
    int*   deg     = (int*)  alloc((size_t)N_NODES * 4);
    float* dinv    = (float*)alloc((size_t)N_NODES * 4);
    int*   row_ptr = (int*)  alloc((size_t)(N_NODES + 1) * 4);
    int*   cursor  = (int*)  alloc((size_t)N_NODES * 4);
    int*   bsum    = (int*)  alloc((size_t)SCAN_NBLK * 4);
    int*   bofs    = (int*)  alloc((size_t)SCAN_NBLK * 4);
    int*   col     = (int*)  alloc((size_t)N_EDGES * 4);
    float* bufA    = (float*)alloc((size_t)N_NODES * HID * 4);
    float* bufB    = (float*)alloc((size_t)N_NODES * HID * 4);

    hipMemsetAsync(deg, 0, (size_t)N_NODES * 4, stream);

    k_degree<<<(N_EDGES + 255) / 256, 256, 0, stream>>>(ei, deg);
    k_dinv<<<(N_NODES + 255) / 256, 256, 0, stream>>>(deg, dinv);
    k_scan_bsum<<<SCAN_NBLK, 256, 0, stream>>>(deg, bsum);
    k_scan_tops<<<1, 128, 0, stream>>>(bsum, bofs, row_ptr);
    k_scan_final<<<SCAN_NBLK, 256, 0, stream>>>(deg, bofs, row_ptr, cursor);
    k_fill<<<(N_EDGES + 255) / 256, 256, 0, stream>>>(ei, cursor, col);

    // layer 1
    k_mm1<<<(N_NODES + 1) / 2, 256, 0, stream>>>(x, W1, dinv, bufA);
    k_agg<0><<<(N_NODES + 3) / 4, 256, 0, stream>>>(bufA, row_ptr, col, dinv, b1,
                                                    nullptr, nullptr, bufB);
    // layer 2
    k_mm_hid<<<N_NODES / 32, 256, 0, stream>>>(bufB, W2, dinv, bufA);
    k_agg<0><<<(N_NODES + 3) / 4, 256, 0, stream>>>(bufA, row_ptr, col, dinv, b2,
                                                    nullptr, nullptr, bufB);
    // layer 3 + fused FC
    k_mm_hid<<<N_NODES / 32, 256, 0, stream>>>(bufB, W3, dinv, bufA);
    k_agg<1><<<(N_NODES + 3) / 4, 256, 0, stream>>>(bufA, row_ptr, col, dinv, b3,
                                                    Wfc, bfc, out);
}

// Round 2
// 735.060 us; speedup vs baseline: 1.1318x; 1.1318x over previous
//
#include <hip/hip_runtime.h>

#define N_NODES 100000
#define N_EDGES 1600000
#define HID 128
#define IN_DIM 5
#define SCAN_ELEMS 1024
#define SCAN_NBLK ((N_NODES + SCAN_ELEMS - 1) / SCAN_ELEMS)  // 98
#define XT_PITCH 132  // 128 + 4 pad: breaks 4-way LDS bank conflict on row reads

// ---------------- CSR build ----------------

__global__ void k_degree(const int* __restrict__ ei, int* __restrict__ deg) {
    int e = blockIdx.x * blockDim.x + threadIdx.x;
    if (e < N_EDGES) atomicAdd(&deg[ei[N_EDGES + e]], 1);
}

__global__ void k_dinv(const int* __restrict__ deg, float* __restrict__ dinv) {
    int i = blockIdx.x * blockDim.x + threadIdx.x;
    if (i < N_NODES) dinv[i] = rsqrtf((float)(deg[i] + 1));  // +1 self-loop
}

__global__ void k_scan_bsum(const int* __restrict__ deg, int* __restrict__ bsum) {
    __shared__ int sm[256];
    int t = threadIdx.x, b = blockIdx.x;
    int base = b * SCAN_ELEMS + t * 4;
    int s = 0;
    if (base + 3 < N_NODES) {
        int4 v = *(const int4*)(deg + base);
        s = v.x + v.y + v.z + v.w;
    } else {
        for (int j = 0; j < 4; ++j) if (base + j < N_NODES) s += deg[base + j];
    }
    sm[t] = s; __syncthreads();
    for (int off = 128; off > 0; off >>= 1) {
        if (t < off) sm[t] += sm[t + off];
        __syncthreads();
    }
    if (t == 0) bsum[b] = sm[0];
}

__global__ void k_scan_tops(const int* __restrict__ bsum, int* __restrict__ bofs,
                            int* __restrict__ row_ptr) {
    __shared__ int sm[128];
    int t = threadIdx.x;
    int v = (t < SCAN_NBLK) ? bsum[t] : 0;
    sm[t] = v; __syncthreads();
    for (int off = 1; off < 128; off <<= 1) {
        int add = (t >= off) ? sm[t - off] : 0;
        __syncthreads();
        sm[t] += add;
        __syncthreads();
    }
    if (t < SCAN_NBLK) bofs[t] = sm[t] - v;  // exclusive
    if (t == 0) row_ptr[N_NODES] = N_EDGES;
}

__global__ void k_scan_final(const int* __restrict__ deg, const int* __restrict__ bofs,
                             int* __restrict__ row_ptr, int* __restrict__ cursor) {
    __shared__ int sm[256];
    int t = threadIdx.x, b = blockIdx.x;
    int base = b * SCAN_ELEMS + t * 4;
    int e0 = 0, e1 = 0, e2 = 0, e3 = 0;
    if (base + 3 < N_NODES) {
        int4 v = *(const int4*)(deg + base);
        e0 = v.x; e1 = v.y; e2 = v.z; e3 = v.w;
    } else {
        if (base     < N_NODES) e0 = deg[base];
        if (base + 1 < N_NODES) e1 = deg[base + 1];
        if (base + 2 < N_NODES) e2 = deg[base + 2];
        if (base + 3 < N_NODES) e3 = deg[base + 3];
    }
    int tot = e0 + e1 + e2 + e3;
    sm[t] = tot; __syncthreads();
    for (int off = 1; off < 256; off <<= 1) {
        int add = (t >= off) ? sm[t - off] : 0;
        __syncthreads();
        sm[t] += add;
        __syncthreads();
    }
    int p0 = sm[t] - tot + bofs[b];
    int p1 = p0 + e0, p2 = p1 + e1, p3 = p2 + e2;
    if (base + 3 < N_NODES) {
        *(int4*)(row_ptr + base) = make_int4(p0, p1, p2, p3);
        *(int4*)(cursor + base)  = make_int4(p0, p1, p2, p3);
    } else {
        if (base     < N_NODES) { row_ptr[base]     = p0; cursor[base]     = p0; }
        if (base + 1 < N_NODES) { row_ptr[base + 1] = p1; cursor[base + 1] = p1; }
        if (base + 2 < N_NODES) { row_ptr[base + 2] = p2; cursor[base + 2] = p2; }
        if (base + 3 < N_NODES) { row_ptr[base + 3] = p3; cursor[base + 3] = p3; }
    }
}

__global__ void k_fill(const int* __restrict__ ei, int* __restrict__ cursor,
                       int* __restrict__ col) {
    int e = blockIdx.x * blockDim.x + threadIdx.x;
    if (e < N_EDGES) {
        int s = ei[e], d = ei[N_EDGES + e];
        int pos = atomicAdd(&cursor[d], 1);
        col[pos] = s;
    }
}

// ---------------- layer 1 matmul (K=5): g = dinv * (x @ W1) ----------------

__global__ void k_mm1(const float* __restrict__ x, const float* __restrict__ W1,
                      const float* __restrict__ dinv, float* __restrict__ g) {
    __shared__ float Wl[IN_DIM * HID];
    int t = threadIdx.x;
    for (int j = t; j < IN_DIM * HID; j += 256) Wl[j] = W1[j];
    __syncthreads();
    int row = blockIdx.x * 2 + (t >> 7);
    int cc  = t & 127;
    if (row >= N_NODES) return;
    float acc = 0.f;
    #pragma unroll
    for (int k = 0; k < IN_DIM; ++k)
        acc += x[row * IN_DIM + k] * Wl[k * HID + cc];
    g[(size_t)row * HID + cc] = dinv[row] * acc;
}

// ---------------- hidden matmul (128x128): G = dinv * (X @ W) ----------------
// 64 rows/block, 256 threads, 4 rows x 8 cols per thread.
// W staged in two 32KB halves; X tile in LDS with pitch 132 (bank-conflict pad).

__global__ __launch_bounds__(256) void k_mm_hid(const float* __restrict__ X,
                                                const float* __restrict__ W,
                                                const float* __restrict__ dinv,
                                                float* __restrict__ G) {
    __shared__ float Wl[64 * HID];           // 32KB: 64 k-rows of W, full 128 cols
    __shared__ float xt[64 * XT_PITCH];      // ~33KB
    int t = threadIdx.x;
    int row0 = blockIdx.x * 64;
    // load X tile: 64 rows x 32 float4 (guarded for last block)
    const float4* X4 = (const float4*)X;
    #pragma unroll
    for (int i = 0; i < 8; ++i) {
        int f = i * 256 + t;          // float4 id 0..2047
        int r = f >> 5;               // tile row
        int c = f & 31;               // float4 col
        float4 v = {0.f, 0.f, 0.f, 0.f};
        if (row0 + r < N_NODES) v = X4[(size_t)(row0 + r) * 32 + c];
        *(float4*)&xt[r * XT_PITCH + c * 4] = v;
    }
    const float4* Wg4 = (const float4*)W;
    float4* Wl4 = (float4*)Wl;
    int cg = t & 15;   // cols cg*8 .. cg*8+7
    int rg = t >> 4;   // rows rg*4 .. rg*4+3
    float4 acc[4][2] = {};
    for (int h = 0; h < 2; ++h) {
        __syncthreads();  // xt ready (h=0) / prev-half compute done (h=1)
        #pragma unroll
        for (int i = 0; i < 8; ++i) Wl4[i * 256 + t] = Wg4[h * 2048 + i * 256 + t];
        __syncthreads();
        #pragma unroll 4
        for (int kk = 0; kk < 64; kk += 4) {
            float4 xr[4];
            #pragma unroll
            for (int r = 0; r < 4; ++r)
                xr[r] = *(const float4*)&xt[(rg * 4 + r) * XT_PITCH + h * 64 + kk];
            #pragma unroll
            for (int q = 0; q < 4; ++q) {
                float4 w0 = Wl4[(kk + q) * 32 + cg * 2];
                float4 w1 = Wl4[(kk + q) * 32 + cg * 2 + 1];
                #pragma unroll
                for (int r = 0; r < 4; ++r) {
                    float xv = (q == 0) ? xr[r].x : (q == 1) ? xr[r].y
                             : (q == 2) ? xr[r].z : xr[r].w;
                    acc[r][0].x += xv * w0.x; acc[r][0].y += xv * w0.y;
                    acc[r][0].z += xv * w0.z; acc[r][0].w += xv * w0.w;
                    acc[r][1].x += xv * w1.x; acc[r][1].y += xv * w1.y;
                    acc[r][1].z += xv * w1.z; acc[r][1].w += xv * w1.w;
                }
            }
        }
    }
    #pragma unroll
    for (int r = 0; r < 4; ++r) {
        int row = row0 + rg * 4 + r;
        if (row < N_NODES) {
            float s = dinv[row];
            float4 a0 = acc[r][0], a1 = acc[r][1];
            a0.x *= s; a0.y *= s; a0.z *= s; a0.w *= s;
            a1.x *= s; a1.y *= s; a1.z *= s; a1.w *= s;
            float4* Gp = (float4*)(G + (size_t)row * HID + cg * 8);
            Gp[0] = a0; Gp[1] = a1;
        }
    }
}

// ---------------- aggregation: out = relu(dinv*(g[i] + sum g[src]) + b) ------
// 2 waves per node (64 features each). col indices batch-loaded coalesced and
// broadcast via shfl; gathers 4-deep unrolled for MLP. FINAL fuses 128->1 FC.

template <int FINAL>
__global__ __launch_bounds__(256) void k_agg(const float* __restrict__ g,
                                             const int* __restrict__ row_ptr,
                                             const int* __restrict__ col,
                                             const float* __restrict__ dinv,
                                             const float* __restrict__ bias,
                                             const float* __restrict__ Wfc,
                                             const float* __restrict__ bfc,
                                             float* __restrict__ out) {
    __shared__ float sm[4];
    int lane = threadIdx.x & 63;
    int w    = threadIdx.x >> 6;              // wave in block: 0..3
    int node = blockIdx.x * 2 + (w >> 1);     // exact: 50000 blocks * 2 = 100000
    int half = w & 1;
    int ofs  = half * 64 + lane;
    float acc = g[(size_t)node * HID + ofs];  // self-loop term
    int start = row_ptr[node], end = row_ptr[node + 1];
    for (int j0 = start; j0 < end; j0 += 64) {
        int idx = j0 + lane;
        int myc = (idx < end) ? col[idx] : 0;
        int cnt = end - j0; if (cnt > 64) cnt = 64;
        int jj = 0;
        for (; jj + 4 <= cnt; jj += 4) {
            int s0 = __shfl(myc, jj);
            int s1 = __shfl(myc, jj + 1);
            int s2 = __shfl(myc, jj + 2);
            int s3 = __shfl(myc, jj + 3);
            float v0 = g[(size_t)s0 * HID + ofs];
            float v1 = g[(size_t)s1 * HID + ofs];
            float v2 = g[(size_t)s2 * HID + ofs];
            float v3 = g[(size_t)s3 * HID + ofs];
            acc += v0 + v1 + v2 + v3;
        }
        for (; jj < cnt; ++jj) {
            int s = __shfl(myc, jj);
            acc += g[(size_t)s * HID + ofs];
        }
    }
    float val = fmaxf(fmaf(dinv[node], acc, bias[ofs]), 0.f);
    if (FINAL == 0) {
        out[(size_t)node * HID + ofs] = val;
    } else {
        float d = val * Wfc[ofs];
        #pragma unroll
        for (int off = 32; off > 0; off >>= 1) d += __shfl_down(d, off, 64);
        if (lane == 0) sm[w] = d;
        __syncthreads();
        if (threadIdx.x == 0)   out[blockIdx.x * 2]     = sm[0] + sm[1] + bfc[0];
        if (threadIdx.x == 128) out[blockIdx.x * 2 + 1] = sm[2] + sm[3] + bfc[0];
    }
}

// ---------------- launcher ----------------

extern "C" void kernel_launch(void* const* d_in, const int* in_sizes, int n_in,
                              void* d_out, int out_size, void* d_ws, size_t ws_size,
                              hipStream_t stream) {
    (void)in_sizes; (void)n_in; (void)out_size; (void)ws_size;
    const float* x   = (const float*)d_in[0];
    const int*   ei  = (const int*)d_in[1];
    const float* W1  = (const float*)d_in[2];
    const float* b1  = (const float*)d_in[3];
    const float* W2  = (const float*)d_in[4];
    const float* b2  = (const float*)d_in[5];
    const float* W3  = (const float*)d_in[6];
    const float* b3  = (const float*)d_in[7];
    const float* Wfc = (const float*)d_in[8];
    const float* bfc = (const float*)d_in[9];
    float* out = (float*)d_out;

    char* p = (char*)d_ws;
    auto alloc = [&](size_t bytes) -> void* {
        void* r = (void*)p;
        p += (bytes + 511) & ~(size_t)511;
        return r;
    };
    int*   deg     = (int*)  alloc((size_t)N_NODES * 4);
    float* dinv    = (float*)alloc((size_t)N_NODES * 4);
    int*   row_ptr = (int*)  alloc((size_t)(N_NODES + 1) * 4);
    int*   cursor  = (int*)  alloc((size_t)N_NODES * 4);
    int*   bsum    = (int*)  alloc((size_t)SCAN_NBLK * 4);
    int*   bofs    = (int*)  alloc((size_t)SCAN_NBLK * 4);
    int*   col     = (int*)  alloc((size_t)N_EDGES * 4);
    float* bufA    = (float*)alloc((size_t)N_NODES * HID * 4);
    float* bufB    = (float*)alloc((size_t)N_NODES * HID * 4);

    hipMemsetAsync(deg, 0, (size_t)N_NODES * 4, stream);

    k_degree<<<(N_EDGES + 255) / 256, 256, 0, stream>>>(ei, deg);
    k_dinv<<<(N_NODES + 255) / 256, 256, 0, stream>>>(deg, dinv);
    k_scan_bsum<<<SCAN_NBLK, 256, 0, stream>>>(deg, bsum);
    k_scan_tops<<<1, 128, 0, stream>>>(bsum, bofs, row_ptr);
    k_scan_final<<<SCAN_NBLK, 256, 0, stream>>>(deg, bofs, row_ptr, cursor);
    k_fill<<<(N_EDGES + 255) / 256, 256, 0, stream>>>(ei, cursor, col);

    int mm_blocks = (N_NODES + 63) / 64;  // 1563

    // layer 1
    k_mm1<<<(N_NODES + 1) / 2, 256, 0, stream>>>(x, W1, dinv, bufA);
    k_agg<0><<<N_NODES / 2, 256, 0, stream>>>(bufA, row_ptr, col, dinv, b1,
                                              nullptr, nullptr, bufB);
    // layer 2
    k_mm_hid<<<mm_blocks, 256, 0, stream>>>(bufB, W2, dinv, bufA);
    k_agg<0><<<N_NODES / 2, 256, 0, stream>>>(bufA, row_ptr, col, dinv, b2,
                                              nullptr, nullptr, bufB);
    // layer 3 + fused FC
    k_mm_hid<<<mm_blocks, 256, 0, stream>>>(bufB, W3, dinv, bufA);
    k_agg<1><<<N_NODES / 2, 256, 0, stream>>>(bufA, row_ptr, col, dinv, b3,
                                              Wfc, bfc, out);
}